// Round 4
// baseline (4109.042 us; speedup 1.0000x reference)
//
#include <hip/hip_runtime.h>
#include <cmath>

// VanillaRNN: B=256, T=128, D=1, H=2048, C=10
// R4: persistent kernel via REGULAR launch (R3's cooperative launch likely
// failed at runtime -> all-zero output, absmax 0.66 == max|ref h|).
// 256 blocks (1/CU, guaranteed by ~400 VGPR usage) x 256 thr.
// W as W_hi+W_lo fp16 in 256 VGPRs/lane (loaded+split once from fp32).
// Per step only h streams (global -> A-frag registers, no LDS in K-loop).
// 4 waves = 4-way K-split, LDS reduction, distributed epilogue.
// Steps separated by per-step MONOTONE two-level barrier (no generations,
// no resets) with explicit __threadfence() release/acquire (cross-XCD safe).

#define B_ 256
#define T_ 128
#define H_ 2048
#define C_ 10

typedef _Float16 half_t;
typedef _Float16 half8 __attribute__((ext_vector_type(8)));
typedef float floatx4 __attribute__((ext_vector_type(4)));

// barrier region layout (dword offsets), one 128B line per counter:
//   LVL0: [t*256 + grp*32]  arrival count, group grp (32 blocks), step t
//   LVL1: [32768 + t*32]    leader count (8 arrivals), step t
//   FLAG: [36864 + t*256 + grp*32]  release flag, group grp, step t
#define LVL1_OFF 32768
#define FLAG_OFF 36864
#define BAR_DWORDS 69632  // 272 KB

__device__ __forceinline__ void step_barrier(unsigned* bar, int t, int grp) {
    __syncthreads();                       // all waves done: stores in L1/L2
    if (threadIdx.x == 0) {
        __threadfence();                   // release: flush to coherence point
        unsigned* c0 = bar + t * 256 + grp * 32;
        unsigned* f0 = bar + FLAG_OFF + t * 256 + grp * 32;
        unsigned o = __hip_atomic_fetch_add(c0, 1u, __ATOMIC_RELAXED,
                                            __HIP_MEMORY_SCOPE_AGENT);
        if (o == 31u) {                    // group leader
            unsigned* c1 = bar + LVL1_OFF + t * 32;
            unsigned o2 = __hip_atomic_fetch_add(c1, 1u, __ATOMIC_RELAXED,
                                                 __HIP_MEMORY_SCOPE_AGENT);
            if (o2 == 7u) {                // last block device-wide: release all
#pragma unroll
                for (int g = 0; g < 8; ++g)
                    __hip_atomic_store(bar + FLAG_OFF + t * 256 + g * 32, 1u,
                                       __ATOMIC_RELAXED, __HIP_MEMORY_SCOPE_AGENT);
            } else {
                while (__hip_atomic_load(f0, __ATOMIC_RELAXED,
                                         __HIP_MEMORY_SCOPE_AGENT) == 0u)
                    __builtin_amdgcn_s_sleep(1);
            }
        } else {
            while (__hip_atomic_load(f0, __ATOMIC_RELAXED,
                                     __HIP_MEMORY_SCOPE_AGENT) == 0u)
                __builtin_amdgcn_s_sleep(1);
        }
        __threadfence();                   // acquire: invalidate L1/L2
    }
    __syncthreads();
}

// ---- persistent RNN kernel ----
__global__ void __launch_bounds__(256, 1) rnn_persist(
    const float* __restrict__ x,   // [B_,T_]
    const float* __restrict__ U,   // [H_]
    const float* __restrict__ W,   // [H_,H_] fp32
    const float* __restrict__ bh,  // [H_]
    half_t* __restrict__ hA,       // ws state buf 0
    half_t* __restrict__ hB,       // ws state buf 1
    float* __restrict__ hf32,      // d_out h_last region
    unsigned* __restrict__ bar)
{
    const int tid  = threadIdx.x;
    const int wave = tid >> 6, lane = tid & 63;
    const int quad = lane >> 4, lq = lane & 15;
    const int id   = blockIdx.x;
    const int grp  = id & 7;                       // id%8 ~ XCD round-robin
    const int m0   = (grp >> 1) * 64;              // all blocks on one XCD share m0
    const int n0   = ((id >> 3) * 2 + (grp & 1)) * 32;

    const int kw = wave * 32 + quad * 8;           // lane k base within 128-chunk

    // ---- one-time: W fragments -> registers (hi+lo fp16), 256 VGPRs ----
    half8 Bhi[16][2], Blo[16][2];
#pragma unroll
    for (int c = 0; c < 16; ++c) {
#pragma unroll
        for (int nt = 0; nt < 2; ++nt) {
            const int gn = n0 + nt * 16 + lq;
            const float4 w0 = *(const float4*)&W[(size_t)gn * H_ + c * 128 + kw];
            const float4 w1 = *(const float4*)&W[(size_t)gn * H_ + c * 128 + kw + 4];
            const float wv[8] = {w0.x, w0.y, w0.z, w0.w, w1.x, w1.y, w1.z, w1.w};
            half8 hi, lo;
#pragma unroll
            for (int j = 0; j < 8; ++j) {
                hi[j] = (half_t)wv[j];
                lo[j] = (half_t)(wv[j] - (float)hi[j]);
            }
            Bhi[c][nt] = hi;
            Blo[c][nt] = lo;
        }
    }

    float uv[2], bv[2];
#pragma unroll
    for (int nt = 0; nt < 2; ++nt) {
        uv[nt] = U[n0 + nt * 16 + lq];
        bv[nt] = bh[n0 + nt * 16 + lq];
    }
    const int gmb = m0 + wave * 16 + quad * 4;     // this lane's 4 output rows

    __shared__ floatx4 red[4][4][2][64];           // [msub][src wave][nt][lane] 32KB

    // ---- step 0: h1 = tanh(x[:,0]*U + bh)  (h0 = 0) ----
#pragma unroll
    for (int nt = 0; nt < 2; ++nt) {
        const int gn = n0 + nt * 16 + lq;
#pragma unroll
        for (int r = 0; r < 4; ++r) {
            const float pre = x[(size_t)(gmb + r) * T_ + 0] * uv[nt] + bv[nt];
            hB[(size_t)(gmb + r) * H_ + gn] = (half_t)tanhf(pre);
        }
    }
    step_barrier(bar, 0, grp);

    // ---- steps t = 1..127 ----
    for (int t = 1; t < T_; ++t) {
        const half_t* hin = (t & 1) ? hB : hA;     // h_t
        half_t* hout      = (t & 1) ? hA : hB;     // h_{t+1}

        floatx4 acc[4][2] = {};

        auto loadA = [&](half8* dst, int c) {
#pragma unroll
            for (int mt = 0; mt < 4; ++mt)
                dst[mt] = *(const half8*)(hin + (size_t)(m0 + mt * 16 + lq) * H_
                                               + c * 128 + kw);
        };

        half8 a[4][4];                             // ring-4, lookahead 3
        loadA(a[0], 0); loadA(a[1], 1); loadA(a[2], 2);
#pragma unroll
        for (int c = 0; c < 16; ++c) {
            if (c + 3 < 16) loadA(a[(c + 3) & 3], c + 3);
            const half8* ac = a[c & 3];
#pragma unroll
            for (int mt = 0; mt < 4; ++mt) {
                acc[mt][0] = __builtin_amdgcn_mfma_f32_16x16x32_f16(ac[mt], Bhi[c][0], acc[mt][0], 0, 0, 0);
                acc[mt][1] = __builtin_amdgcn_mfma_f32_16x16x32_f16(ac[mt], Bhi[c][1], acc[mt][1], 0, 0, 0);
                acc[mt][0] = __builtin_amdgcn_mfma_f32_16x16x32_f16(ac[mt], Blo[c][0], acc[mt][0], 0, 0, 0);
                acc[mt][1] = __builtin_amdgcn_mfma_f32_16x16x32_f16(ac[mt], Blo[c][1], acc[mt][1], 0, 0, 0);
            }
        }

        // ---- 4-way K-split reduction through LDS ----
#pragma unroll
        for (int mt = 0; mt < 4; ++mt)
#pragma unroll
            for (int nt = 0; nt < 2; ++nt)
                red[mt][wave][nt][lane] = acc[mt][nt];
        __syncthreads();
        floatx4 s[2];
#pragma unroll
        for (int nt = 0; nt < 2; ++nt)
            s[nt] = red[wave][0][nt][lane] + red[wave][1][nt][lane]
                  + red[wave][2][nt][lane] + red[wave][3][nt][lane];

        // ---- epilogue: +x_t*U +bh, tanh, store (wave owns msub == wave) ----
        float xr[4];
#pragma unroll
        for (int r = 0; r < 4; ++r) xr[r] = x[(size_t)(gmb + r) * T_ + t];
#pragma unroll
        for (int nt = 0; nt < 2; ++nt) {
            const int gn = n0 + nt * 16 + lq;
#pragma unroll
            for (int r = 0; r < 4; ++r) {
                const float pre = s[nt][r] + xr[r] * uv[nt] + bv[nt];
                const float hv = tanhf(pre);
                hout[(size_t)(gmb + r) * H_ + gn] = (half_t)hv;
                if (t == T_ - 1) hf32[(size_t)(gmb + r) * H_ + gn] = hv;
            }
        }
        if (t < T_ - 1) step_barrier(bar, t, grp);
    }
}

// ---- output projection: out[b,c] = h[b,:] . V[c,:] + bp[c] ----
__global__ __launch_bounds__(256) void rnn_out(
    const float* __restrict__ h, const float* __restrict__ V,
    const float* __restrict__ bp, float* __restrict__ outp) {
    const int b = blockIdx.x;
    const int tid = threadIdx.x;
    float acc[C_] = {};
    for (int k = tid; k < H_; k += 256) {
        const float hv = h[(size_t)b * H_ + k];
#pragma unroll
        for (int c = 0; c < C_; ++c) acc[c] += hv * V[(size_t)c * H_ + k];
    }
#pragma unroll
    for (int c = 0; c < C_; ++c)
#pragma unroll
        for (int off = 32; off > 0; off >>= 1)
            acc[c] += __shfl_down(acc[c], off, 64);
    __shared__ float partial[4][C_];
    const int wave = tid >> 6, lane = tid & 63;
    if (lane == 0)
#pragma unroll
        for (int c = 0; c < C_; ++c) partial[wave][c] = acc[c];
    __syncthreads();
    if (tid < C_)
        outp[b * C_ + tid] = partial[0][tid] + partial[1][tid]
                           + partial[2][tid] + partial[3][tid] + bp[tid];
}

extern "C" void kernel_launch(void* const* d_in, const int* in_sizes, int n_in,
                              void* d_out, int out_size, void* d_ws, size_t ws_size,
                              hipStream_t stream) {
    const float* x  = (const float*)d_in[0];
    const float* U  = (const float*)d_in[1];
    const float* W  = (const float*)d_in[2];
    const float* V  = (const float*)d_in[3];
    const float* bh = (const float*)d_in[4];
    const float* bp = (const float*)d_in[5];

    float* out_h = (float*)d_out;                  // [B_*H_] fp32 h_last
    float* outp  = out_h + (size_t)B_ * H_;        // [B_*C_]

    half_t* hA = (half_t*)d_ws;                                   // 1 MB
    half_t* hB = hA + (size_t)B_ * H_;                            // 1 MB
    unsigned* bar = (unsigned*)((char*)d_ws + 4u * 1024 * 1024);  // 272 KB

    hipMemsetAsync(bar, 0, BAR_DWORDS * sizeof(unsigned), stream);

    rnn_persist<<<dim3(256), dim3(256), 0, stream>>>(
        x, U, W, bh, hA, hB, out_h, bar);

    rnn_out<<<dim3(B_), dim3(256), 0, stream>>>(out_h, V, bp, outp);
}

// Round 6
// 2264.062 us; speedup vs baseline: 1.8149x; 1.8149x over previous
//
#include <hip/hip_runtime.h>
#include <cmath>

// VanillaRNN: B=256, T=128, D=1, H=2048, C=10
// R6: == R5 with the A-chunk stride bug fixed (u64 units: chunk = 32 u64,
// R5 wrongly used 16 -> read wrong k-slices -> absmax 1.06).
// Persistent kernel (regular launch, 256 blocks = 1/CU x 256 thr).
// W as W_hi+W_lo fp16 in ~256 regs/lane. h exchanged via relaxed AGENT-scope
// 8B atomics (sc0/sc1 -> MALL-coherent, bypasses L1/L2) => NO cache-op fences
// in the step loop. Read-only x/U/bh/W normally cached, never invalidated.
// Barrier: 4 independent per-m-group (64-block) monotone 2-level rails,
// per-step slots, relaxed atomics + compiler-only barriers.

#define B_ 256
#define T_ 128
#define H_ 2048
#define C_ 10

typedef _Float16 half_t;
typedef _Float16 half8 __attribute__((ext_vector_type(8)));
typedef _Float16 half4v __attribute__((ext_vector_type(4)));
typedef float floatx4 __attribute__((ext_vector_type(4)));
typedef unsigned long long u64;

struct A16 { u64 lo, hi; };   // one 16B MFMA A-fragment moved as 2x8B atomics

// barrier region (dword offsets; every counter on its own 128B line):
//   C0  [(t*8+grp)*32]         : 32-block arrival count (group grp, step t)
//   C1  [C1_OFF+(t*4+g)*32]    : 2 sub-rail leaders (m-group g, step t)
//   FLG [FLAG_OFF+(t*8+grp)*32]: release flag (group grp, step t)
#define C1_OFF   32768
#define FLAG_OFF 49152
#define BAR_DWORDS 81920  // 320 KB

__device__ __forceinline__ void step_barrier(unsigned* bar, int t, int grp) {
    __syncthreads();  // drains this block's sc1 h-stores (vmcnt0 before s_barrier)
    if (threadIdx.x == 0) {
        asm volatile("" ::: "memory");     // no compiler motion across arrival
        const int g = grp >> 1;
        unsigned* c0 = bar + (t * 8 + grp) * 32;
        unsigned* f  = bar + FLAG_OFF + (t * 8 + grp) * 32;
        unsigned o = __hip_atomic_fetch_add(c0, 1u, __ATOMIC_RELAXED,
                                            __HIP_MEMORY_SCOPE_AGENT);
        if (o == 31u) {  // sub-rail leader
            unsigned* c1 = bar + C1_OFF + (t * 4 + g) * 32;
            unsigned o2 = __hip_atomic_fetch_add(c1, 1u, __ATOMIC_RELAXED,
                                                 __HIP_MEMORY_SCOPE_AGENT);
            if (o2 == 1u) {  // last leader of the m-group: release both rails
                __hip_atomic_store(bar + FLAG_OFF + (t * 8 + g * 2) * 32, 1u,
                                   __ATOMIC_RELAXED, __HIP_MEMORY_SCOPE_AGENT);
                __hip_atomic_store(bar + FLAG_OFF + (t * 8 + g * 2 + 1) * 32, 1u,
                                   __ATOMIC_RELAXED, __HIP_MEMORY_SCOPE_AGENT);
            } else {
                while (!__hip_atomic_load(f, __ATOMIC_RELAXED,
                                          __HIP_MEMORY_SCOPE_AGENT))
                    __builtin_amdgcn_s_sleep(1);
            }
        } else {
            while (!__hip_atomic_load(f, __ATOMIC_RELAXED,
                                      __HIP_MEMORY_SCOPE_AGENT))
                __builtin_amdgcn_s_sleep(1);
        }
        asm volatile("" ::: "memory");     // no hoisting of h-loads above poll
    }
    __syncthreads();
}

__device__ __forceinline__ float fast_tanh(float v) {
    // 1 - 2/(e^{2v}+1); large +v -> exp=inf -> 1; large -v -> exp=0 -> -1
    return 1.0f - 2.0f / (__expf(2.0f * v) + 1.0f);
}

// ---- persistent RNN kernel ----
__global__ void __launch_bounds__(256, 1) rnn_persist(
    const float* __restrict__ x,   // [B_,T_]
    const float* __restrict__ U,   // [H_]
    const float* __restrict__ W,   // [H_,H_] fp32
    const float* __restrict__ bh,  // [H_]
    half_t* __restrict__ hA,       // ws state buf 0 (sc1 domain)
    half_t* __restrict__ hB,       // ws state buf 1 (sc1 domain)
    float* __restrict__ hf32,      // d_out h_last region
    unsigned* __restrict__ bar)
{
    const int tid  = threadIdx.x;
    const int wave = tid >> 6, lane = tid & 63;
    const int quad = lane >> 4, lq = lane & 15;
    const int id   = blockIdx.x;
    const int grp  = id & 7;
    const int g    = grp >> 1, p = grp & 1;
    const int m0   = g * 64;                      // m-group g owns 64 rows
    const int n0   = ((id >> 3) * 2 + p) * 32;    // 64 n-tiles of 32

    const int kw = wave * 32 + quad * 8;          // lane k base per 128-chunk

    // ---- one-time: W fragments -> registers (hi+lo fp16), ~256 regs ----
    half8 Bhi[16][2], Blo[16][2];
#pragma unroll
    for (int c = 0; c < 16; ++c) {
#pragma unroll
        for (int nt = 0; nt < 2; ++nt) {
            const int gn = n0 + nt * 16 + lq;
            const float4 w0 = *(const float4*)&W[(size_t)gn * H_ + c * 128 + kw];
            const float4 w1 = *(const float4*)&W[(size_t)gn * H_ + c * 128 + kw + 4];
            const float wv[8] = {w0.x, w0.y, w0.z, w0.w, w1.x, w1.y, w1.z, w1.w};
            half8 hi, lo;
#pragma unroll
            for (int j = 0; j < 8; ++j) {
                hi[j] = (half_t)wv[j];
                lo[j] = (half_t)(wv[j] - (float)hi[j]);
            }
            Bhi[c][nt] = hi;
            Blo[c][nt] = lo;
        }
    }

    float uv[2], bv[2];
#pragma unroll
    for (int nt = 0; nt < 2; ++nt) {
        uv[nt] = U[n0 + nt * 16 + lq];
        bv[nt] = bh[n0 + nt * 16 + lq];
    }
    const int gmb = m0 + wave * 16 + quad * 4;    // owner-lane 4 output rows

    __shared__ floatx4 red[4][4][2][64];          // k-split reduction, 32 KB
    __shared__ float Sm[64][33];                  // epilogue transpose, 8.4 KB

    const int prow = tid >> 2;                    // pack thread: row 0..63
    const int pc0  = (tid & 3) * 8;               // 8-col chunk

    // ---- step 0: h1 = tanh(x[:,0]*U + bh)  (h0 = 0, no matmul) ----
    {
        const float xb = x[(size_t)(m0 + prow) * T_ + 0];
        const float4 u0 = *(const float4*)&U[n0 + pc0];
        const float4 u1 = *(const float4*)&U[n0 + pc0 + 4];
        const float4 b0 = *(const float4*)&bh[n0 + pc0];
        const float4 b1 = *(const float4*)&bh[n0 + pc0 + 4];
        const float uva[8] = {u0.x, u0.y, u0.z, u0.w, u1.x, u1.y, u1.z, u1.w};
        const float bva[8] = {b0.x, b0.y, b0.z, b0.w, b1.x, b1.y, b1.z, b1.w};
        half4v ha, hb2;
#pragma unroll
        for (int j = 0; j < 4; ++j) {
            ha[j]  = (half_t)fast_tanh(xb * uva[j] + bva[j]);
            hb2[j] = (half_t)fast_tanh(xb * uva[4 + j] + bva[4 + j]);
        }
        u64* dst = (u64*)(hB + (size_t)(m0 + prow) * H_ + n0 + pc0);
        __hip_atomic_store(dst, __builtin_bit_cast(u64, ha),
                           __ATOMIC_RELAXED, __HIP_MEMORY_SCOPE_AGENT);
        __hip_atomic_store(dst + 1, __builtin_bit_cast(u64, hb2),
                           __ATOMIC_RELAXED, __HIP_MEMORY_SCOPE_AGENT);
    }
    step_barrier(bar, 0, grp);

    // ---- steps t = 1..127 ----
    for (int t = 1; t < T_; ++t) {
        const half_t* hin = (t & 1) ? hB : hA;    // h_t
        half_t* hout      = (t & 1) ? hA : hB;    // h_{t+1}

        floatx4 acc[4][2] = {};

        const u64* base[4];
#pragma unroll
        for (int mt = 0; mt < 4; ++mt)
            base[mt] = (const u64*)(hin + (size_t)(m0 + mt * 16 + lq) * H_ + kw);

        A16 ring[5][4];                           // ring-5, lookahead 4
        auto loadA = [&](A16* dst, int c) {
#pragma unroll
            for (int mt = 0; mt < 4; ++mt) {
                // chunk c = 128 halfs = 256 B = 32 u64  (R5 bug: used 16)
                const u64* q = base[mt] + (size_t)c * 32;
                dst[mt].lo = __hip_atomic_load(q, __ATOMIC_RELAXED,
                                               __HIP_MEMORY_SCOPE_AGENT);
                dst[mt].hi = __hip_atomic_load(q + 1, __ATOMIC_RELAXED,
                                               __HIP_MEMORY_SCOPE_AGENT);
            }
        };
        loadA(ring[0], 0); loadA(ring[1], 1); loadA(ring[2], 2); loadA(ring[3], 3);
#pragma unroll
        for (int c = 0; c < 16; ++c) {
            if (c + 4 < 16) loadA(ring[(c + 4) % 5], c + 4);
            const A16* ac = ring[c % 5];
#pragma unroll
            for (int mt = 0; mt < 4; ++mt) {
                const half8 av = __builtin_bit_cast(half8, ac[mt]);
                acc[mt][0] = __builtin_amdgcn_mfma_f32_16x16x32_f16(av, Bhi[c][0], acc[mt][0], 0, 0, 0);
                acc[mt][1] = __builtin_amdgcn_mfma_f32_16x16x32_f16(av, Bhi[c][1], acc[mt][1], 0, 0, 0);
                acc[mt][0] = __builtin_amdgcn_mfma_f32_16x16x32_f16(av, Blo[c][0], acc[mt][0], 0, 0, 0);
                acc[mt][1] = __builtin_amdgcn_mfma_f32_16x16x32_f16(av, Blo[c][1], acc[mt][1], 0, 0, 0);
            }
        }

        // ---- 4-way K-split reduction ----
#pragma unroll
        for (int mt = 0; mt < 4; ++mt)
#pragma unroll
            for (int nt = 0; nt < 2; ++nt)
                red[mt][wave][nt][lane] = acc[mt][nt];
        __syncthreads();

        // owner wave: sum, +x*U+bh, tanh -> Sm (fp32)
        float xr[4];
#pragma unroll
        for (int r = 0; r < 4; ++r) xr[r] = x[(size_t)(gmb + r) * T_ + t];
#pragma unroll
        for (int nt = 0; nt < 2; ++nt) {
            const floatx4 s = red[wave][0][nt][lane] + red[wave][1][nt][lane]
                            + red[wave][2][nt][lane] + red[wave][3][nt][lane];
#pragma unroll
            for (int r = 0; r < 4; ++r) {
                const float pre = s[r] + xr[r] * uv[nt] + bv[nt];
                Sm[wave * 16 + quad * 4 + r][nt * 16 + lq] = fast_tanh(pre);
            }
        }
        __syncthreads();

        // pack 16B/thread, publish via 2x8B sc1 atomic stores
        {
            float fv[8];
#pragma unroll
            for (int j = 0; j < 8; ++j) fv[j] = Sm[prow][pc0 + j];
            half4v ha, hb2;
#pragma unroll
            for (int j = 0; j < 4; ++j) {
                ha[j] = (half_t)fv[j];
                hb2[j] = (half_t)fv[4 + j];
            }
            u64* dst = (u64*)(hout + (size_t)(m0 + prow) * H_ + n0 + pc0);
            __hip_atomic_store(dst, __builtin_bit_cast(u64, ha),
                               __ATOMIC_RELAXED, __HIP_MEMORY_SCOPE_AGENT);
            __hip_atomic_store(dst + 1, __builtin_bit_cast(u64, hb2),
                               __ATOMIC_RELAXED, __HIP_MEMORY_SCOPE_AGENT);
            if (t == T_ - 1) {   // final step: fp32 h_last (normal stores;
                                 // end-of-kernel release covers rnn_out)
                float* fd = hf32 + (size_t)(m0 + prow) * H_ + n0 + pc0;
#pragma unroll
                for (int j = 0; j < 8; ++j) fd[j] = fv[j];
            }
        }
        if (t < T_ - 1) step_barrier(bar, t, grp);
    }
}

// ---- output projection: out[b,c] = h[b,:] . V[c,:] + bp[c] ----
__global__ __launch_bounds__(256) void rnn_out(
    const float* __restrict__ h, const float* __restrict__ V,
    const float* __restrict__ bp, float* __restrict__ outp) {
    const int b = blockIdx.x;
    const int tid = threadIdx.x;
    float acc[C_] = {};
    for (int k = tid; k < H_; k += 256) {
        const float hv = h[(size_t)b * H_ + k];
#pragma unroll
        for (int c = 0; c < C_; ++c) acc[c] += hv * V[(size_t)c * H_ + k];
    }
#pragma unroll
    for (int c = 0; c < C_; ++c)
#pragma unroll
        for (int off = 32; off > 0; off >>= 1)
            acc[c] += __shfl_down(acc[c], off, 64);
    __shared__ float partial[4][C_];
    const int wave = tid >> 6, lane = tid & 63;
    if (lane == 0)
#pragma unroll
        for (int c = 0; c < C_; ++c) partial[wave][c] = acc[c];
    __syncthreads();
    if (tid < C_)
        outp[b * C_ + tid] = partial[0][tid] + partial[1][tid]
                           + partial[2][tid] + partial[3][tid] + bp[tid];
}

extern "C" void kernel_launch(void* const* d_in, const int* in_sizes, int n_in,
                              void* d_out, int out_size, void* d_ws, size_t ws_size,
                              hipStream_t stream) {
    const float* x  = (const float*)d_in[0];
    const float* U  = (const float*)d_in[1];
    const float* W  = (const float*)d_in[2];
    const float* V  = (const float*)d_in[3];
    const float* bh = (const float*)d_in[4];
    const float* bp = (const float*)d_in[5];

    float* out_h = (float*)d_out;                 // [B_*H_] fp32 h_last
    float* outp  = out_h + (size_t)B_ * H_;       // [B_*C_]

    half_t* hA = (half_t*)d_ws;                                  // 1 MB
    half_t* hB = hA + (size_t)B_ * H_;                           // 1 MB
    unsigned* bar = (unsigned*)((char*)d_ws + 2u * 1024 * 1024); // 320 KB

    hipMemsetAsync(bar, 0, BAR_DWORDS * sizeof(unsigned), stream);

    rnn_persist<<<dim3(256), dim3(256), 0, stream>>>(
        x, U, W, bh, hA, hB, out_h, bar);

    rnn_out<<<dim3(B_), dim3(256), 0, stream>>>(out_h, V, bp, outp);
}

// Round 7
// 1926.168 us; speedup vs baseline: 2.1333x; 1.1754x over previous
//
#include <hip/hip_runtime.h>
#include <cmath>

// VanillaRNN: B=256, T=128, D=1, H=2048, C=10
// R7: == R6 semantics, but the h-exchange consumer path is LINE-COALESCED:
// each block stages its m-slab chunk [64 rows x 128 k] into LDS with
// consecutive-lane sc1 loads (full 64B-line utilization, kills the 4x MALL
// over-fetch that bounded R6), then MFMA A-frags come from LDS via
// XOR-swizzled ds_read_b128. Barrier: single-level 64-arrival per-m-group
// rails, per-step slots. W stays in ~256 regs/lane as fp16 hi+lo.

#define B_ 256
#define T_ 128
#define H_ 2048
#define C_ 10

typedef _Float16 half_t;
typedef _Float16 half8 __attribute__((ext_vector_type(8)));
typedef _Float16 half4v __attribute__((ext_vector_type(4)));
typedef float floatx4 __attribute__((ext_vector_type(4)));
typedef unsigned long long u64;

struct A16 { u64 lo, hi; };   // 16B moved as 2x8B sc1 atomics

// barrier region (dword offsets; each counter on its own 128B line):
//   C0  [(t*4+g)*32]           : 64-block arrival count (m-group g, step t)
//   FLG [FLAG_OFF+(t*4+g)*32]  : release flag (m-group g, step t)
#define FLAG_OFF 16384
#define BAR_DWORDS 32768  // 128 KB

__device__ __forceinline__ void step_barrier(unsigned* bar, int t, int g) {
    __syncthreads();  // drains this block's sc1 h-stores (vmcnt0 before s_barrier)
    if (threadIdx.x == 0) {
        asm volatile("" ::: "memory");
        unsigned* c0 = bar + (t * 4 + g) * 32;
        unsigned* f  = bar + FLAG_OFF + (t * 4 + g) * 32;
        unsigned o = __hip_atomic_fetch_add(c0, 1u, __ATOMIC_RELAXED,
                                            __HIP_MEMORY_SCOPE_AGENT);
        if (o == 63u) {  // last block of the m-group: release
            __hip_atomic_store(f, 1u, __ATOMIC_RELAXED, __HIP_MEMORY_SCOPE_AGENT);
        } else {
            while (!__hip_atomic_load(f, __ATOMIC_RELAXED,
                                      __HIP_MEMORY_SCOPE_AGENT))
                __builtin_amdgcn_s_sleep(1);
        }
        asm volatile("" ::: "memory");
    }
    __syncthreads();
}

__device__ __forceinline__ float fast_tanh(float v) {
    return 1.0f - 2.0f / (__expf(2.0f * v) + 1.0f);
}

// ---- persistent RNN kernel ----
__global__ void __launch_bounds__(256, 1) rnn_persist(
    const float* __restrict__ x,   // [B_,T_]
    const float* __restrict__ U,   // [H_]
    const float* __restrict__ W,   // [H_,H_] fp32
    const float* __restrict__ bh,  // [H_]
    half_t* __restrict__ hA,       // ws state buf 0 (sc1 domain)
    half_t* __restrict__ hB,       // ws state buf 1 (sc1 domain)
    float* __restrict__ hf32,      // d_out h_last region
    unsigned* __restrict__ bar)
{
    const int tid  = threadIdx.x;
    const int wave = tid >> 6, lane = tid & 63;
    const int quad = lane >> 4, lq = lane & 15;
    const int id   = blockIdx.x;
    const int grp  = id & 7;
    const int g    = grp >> 1, p = grp & 1;
    const int m0   = g * 64;                      // m-group g owns 64 rows
    const int n0   = ((id >> 3) * 2 + p) * 32;    // 64 n-tiles of 32

    const int kw = wave * 32 + quad * 8;          // lane k base per 128-chunk

    // ---- one-time: W fragments -> registers (hi+lo fp16), ~256 regs ----
    half8 Bhi[16][2], Blo[16][2];
#pragma unroll
    for (int c = 0; c < 16; ++c) {
#pragma unroll
        for (int nt = 0; nt < 2; ++nt) {
            const int gn = n0 + nt * 16 + lq;
            const float4 w0 = *(const float4*)&W[(size_t)gn * H_ + c * 128 + kw];
            const float4 w1 = *(const float4*)&W[(size_t)gn * H_ + c * 128 + kw + 4];
            const float wv[8] = {w0.x, w0.y, w0.z, w0.w, w1.x, w1.y, w1.z, w1.w};
            half8 hi, lo;
#pragma unroll
            for (int j = 0; j < 8; ++j) {
                hi[j] = (half_t)wv[j];
                lo[j] = (half_t)(wv[j] - (float)hi[j]);
            }
            Bhi[c][nt] = hi;
            Blo[c][nt] = lo;
        }
    }

    float uv[2], bv[2];
#pragma unroll
    for (int nt = 0; nt < 2; ++nt) {
        uv[nt] = U[n0 + nt * 16 + lq];
        bv[nt] = bh[n0 + nt * 16 + lq];
    }
    const int gmb = m0 + wave * 16 + quad * 4;    // owner-lane 4 output rows

    // LDS: A-chunk stage [2 bufs][16 kappa][64 m] of 16B units, XOR-swizzled
    __shared__ A16 Ast[2][1024];                  // 32 KB
    __shared__ floatx4 red[4][4][2][64];          // k-split reduction, 32 KB
    __shared__ float Sm[64][33];                  // epilogue transpose, 8.4 KB

    const int prow = tid >> 2;                    // pack thread: row 0..63
    const int pc0  = (tid & 3) * 8;               // 8-col chunk

    // staging thread slots: s = it*256+tid; kappa = s&15 (fast -> coalesced),
    // m = s>>4; LDS unit = kappa*64 + (m ^ (kappa&7))
    // reader: kappa_r = wave*4+quad; m_r = mt*16+lq; same unit formula.
    const int kr = wave * 4 + quad;               // reader kappa

    // ---- step 0: h1 = tanh(x[:,0]*U + bh)  (h0 = 0, no matmul) ----
    {
        const float xb = x[(size_t)(m0 + prow) * T_ + 0];
        const float4 u0 = *(const float4*)&U[n0 + pc0];
        const float4 u1 = *(const float4*)&U[n0 + pc0 + 4];
        const float4 b0 = *(const float4*)&bh[n0 + pc0];
        const float4 b1 = *(const float4*)&bh[n0 + pc0 + 4];
        const float uva[8] = {u0.x, u0.y, u0.z, u0.w, u1.x, u1.y, u1.z, u1.w};
        const float bva[8] = {b0.x, b0.y, b0.z, b0.w, b1.x, b1.y, b1.z, b1.w};
        half4v ha, hb2;
#pragma unroll
        for (int j = 0; j < 4; ++j) {
            ha[j]  = (half_t)fast_tanh(xb * uva[j] + bva[j]);
            hb2[j] = (half_t)fast_tanh(xb * uva[4 + j] + bva[4 + j]);
        }
        u64* dst = (u64*)(hB + (size_t)(m0 + prow) * H_ + n0 + pc0);
        __hip_atomic_store(dst, __builtin_bit_cast(u64, ha),
                           __ATOMIC_RELAXED, __HIP_MEMORY_SCOPE_AGENT);
        __hip_atomic_store(dst + 1, __builtin_bit_cast(u64, hb2),
                           __ATOMIC_RELAXED, __HIP_MEMORY_SCOPE_AGENT);
    }
    step_barrier(bar, 0, g);

    // ---- steps t = 1..127 ----
    for (int t = 1; t < T_; ++t) {
        const half_t* hin = (t & 1) ? hB : hA;    // h_t
        half_t* hout      = (t & 1) ? hA : hB;    // h_{t+1}

        floatx4 acc[4][2] = {};

        // issue coalesced sc1 loads for a chunk into regs
        auto issue = [&](A16* st, int chunk) {
#pragma unroll
            for (int it = 0; it < 4; ++it) {
                const int s = it * 256 + tid;
                const int ka = s & 15, m = s >> 4;
                const u64* q = (const u64*)(hin + (size_t)(m0 + m) * H_
                                                 + chunk * 128 + ka * 8);
                st[it].lo = __hip_atomic_load(q, __ATOMIC_RELAXED,
                                              __HIP_MEMORY_SCOPE_AGENT);
                st[it].hi = __hip_atomic_load(q + 1, __ATOMIC_RELAXED,
                                              __HIP_MEMORY_SCOPE_AGENT);
            }
        };
        auto commit = [&](int bufi, const A16* st) {
#pragma unroll
            for (int it = 0; it < 4; ++it) {
                const int s = it * 256 + tid;
                const int ka = s & 15, m = s >> 4;
                Ast[bufi][ka * 64 + (m ^ (ka & 7))] = st[it];
            }
        };
        auto compute = [&](int bufi, int c) {
#pragma unroll
            for (int mt = 0; mt < 4; ++mt) {
                const int unit = kr * 64 + ((mt * 16 + lq) ^ (kr & 7));
                const half8 av = __builtin_bit_cast(half8, Ast[bufi][unit]);
                acc[mt][0] = __builtin_amdgcn_mfma_f32_16x16x32_f16(av, Bhi[c][0], acc[mt][0], 0, 0, 0);
                acc[mt][1] = __builtin_amdgcn_mfma_f32_16x16x32_f16(av, Bhi[c][1], acc[mt][1], 0, 0, 0);
                acc[mt][0] = __builtin_amdgcn_mfma_f32_16x16x32_f16(av, Blo[c][0], acc[mt][0], 0, 0, 0);
                acc[mt][1] = __builtin_amdgcn_mfma_f32_16x16x32_f16(av, Blo[c][1], acc[mt][1], 0, 0, 0);
            }
        };

        {   // prologue: stage chunk 0
            A16 st[4];
            issue(st, 0); commit(0, st);
        }
        __syncthreads();
        int buf = 0;
#pragma unroll
        for (int c = 0; c < 16; ++c) {
            A16 st[4];
            if (c < 15) issue(st, c + 1);   // loads in flight across MFMAs
            compute(buf, c);
            if (c < 15) commit(buf ^ 1, st);
            __syncthreads();
            buf ^= 1;
        }

        // ---- 4-way K-split reduction ----
#pragma unroll
        for (int mt = 0; mt < 4; ++mt)
#pragma unroll
            for (int nt = 0; nt < 2; ++nt)
                red[mt][wave][nt][lane] = acc[mt][nt];
        __syncthreads();

        // owner wave: sum, +x*U+bh, tanh -> Sm (fp32)
        float xr[4];
#pragma unroll
        for (int r = 0; r < 4; ++r) xr[r] = x[(size_t)(gmb + r) * T_ + t];
#pragma unroll
        for (int nt = 0; nt < 2; ++nt) {
            const floatx4 s = red[wave][0][nt][lane] + red[wave][1][nt][lane]
                            + red[wave][2][nt][lane] + red[wave][3][nt][lane];
#pragma unroll
            for (int r = 0; r < 4; ++r) {
                const float pre = s[r] + xr[r] * uv[nt] + bv[nt];
                Sm[wave * 16 + quad * 4 + r][nt * 16 + lq] = fast_tanh(pre);
            }
        }
        __syncthreads();

        // pack 16B/thread, publish via 2x8B sc1 atomic stores
        {
            float fv[8];
#pragma unroll
            for (int j = 0; j < 8; ++j) fv[j] = Sm[prow][pc0 + j];
            half4v ha, hb2;
#pragma unroll
            for (int j = 0; j < 4; ++j) {
                ha[j] = (half_t)fv[j];
                hb2[j] = (half_t)fv[4 + j];
            }
            u64* dst = (u64*)(hout + (size_t)(m0 + prow) * H_ + n0 + pc0);
            __hip_atomic_store(dst, __builtin_bit_cast(u64, ha),
                               __ATOMIC_RELAXED, __HIP_MEMORY_SCOPE_AGENT);
            __hip_atomic_store(dst + 1, __builtin_bit_cast(u64, hb2),
                               __ATOMIC_RELAXED, __HIP_MEMORY_SCOPE_AGENT);
            if (t == T_ - 1) {   // final step: fp32 h_last to d_out
                float* fd = hf32 + (size_t)(m0 + prow) * H_ + n0 + pc0;
#pragma unroll
                for (int j = 0; j < 8; ++j) fd[j] = fv[j];
            }
        }
        if (t < T_ - 1) step_barrier(bar, t, g);
    }
}

// ---- output projection: out[b,c] = h[b,:] . V[c,:] + bp[c] ----
__global__ __launch_bounds__(256) void rnn_out(
    const float* __restrict__ h, const float* __restrict__ V,
    const float* __restrict__ bp, float* __restrict__ outp) {
    const int b = blockIdx.x;
    const int tid = threadIdx.x;
    float acc[C_] = {};
    for (int k = tid; k < H_; k += 256) {
        const float hv = h[(size_t)b * H_ + k];
#pragma unroll
        for (int c = 0; c < C_; ++c) acc[c] += hv * V[(size_t)c * H_ + k];
    }
#pragma unroll
    for (int c = 0; c < C_; ++c)
#pragma unroll
        for (int off = 32; off > 0; off >>= 1)
            acc[c] += __shfl_down(acc[c], off, 64);
    __shared__ float partial[4][C_];
    const int wave = tid >> 6, lane = tid & 63;
    if (lane == 0)
#pragma unroll
        for (int c = 0; c < C_; ++c) partial[wave][c] = acc[c];
    __syncthreads();
    if (tid < C_)
        outp[b * C_ + tid] = partial[0][tid] + partial[1][tid]
                           + partial[2][tid] + partial[3][tid] + bp[tid];
}

extern "C" void kernel_launch(void* const* d_in, const int* in_sizes, int n_in,
                              void* d_out, int out_size, void* d_ws, size_t ws_size,
                              hipStream_t stream) {
    const float* x  = (const float*)d_in[0];
    const float* U  = (const float*)d_in[1];
    const float* W  = (const float*)d_in[2];
    const float* V  = (const float*)d_in[3];
    const float* bh = (const float*)d_in[4];
    const float* bp = (const float*)d_in[5];

    float* out_h = (float*)d_out;                 // [B_*H_] fp32 h_last
    float* outp  = out_h + (size_t)B_ * H_;       // [B_*C_]

    half_t* hA = (half_t*)d_ws;                                  // 1 MB
    half_t* hB = hA + (size_t)B_ * H_;                           // 1 MB
    unsigned* bar = (unsigned*)((char*)d_ws + 2u * 1024 * 1024); // 128 KB

    hipMemsetAsync(bar, 0, BAR_DWORDS * sizeof(unsigned), stream);

    rnn_persist<<<dim3(256), dim3(256), 0, stream>>>(
        x, U, W, bh, hA, hB, out_h, bar);

    rnn_out<<<dim3(B_), dim3(256), 0, stream>>>(out_h, V, bp, outp);
}